// Round 5
// baseline (426.613 us; speedup 1.0000x reference)
//
#include <hip/hip_runtime.h>

// Problem constants
#define BATCH  64
#define CH     64
#define WFLAT  16384              // 128*128
#define KSPLIT 16                 // 1024 blocks = 4 blocks/CU
#define KPER   (WFLAT / KSPLIT)   // 1024
#define BK     128                // K-chunk staged in LDS per iteration
#define NT     (KPER / BK)        // 8 iterations per block
#define LDSS   136                // LDS row stride in bf16 elements (128 + 8 pad)
#define GSIZE  (CH * CH)          // 4096

typedef short bf16x8 __attribute__((ext_vector_type(8)));
typedef float f32x4  __attribute__((ext_vector_type(4)));

__device__ __forceinline__ unsigned int f2bf(float f) {
  // fp32 -> bf16 bits, round-to-nearest-even; low 16 bits valid
  unsigned int u = __float_as_uint(f);
  return (u + 0x7FFFu + ((u >> 16) & 1u)) >> 16;
}

// ---------------------------------------------------------------------------
// Kernel 1: batched Gram partials with K-split. NO atomics: block (b, ks)
// writes its 64x64 partial to gpart[b][ks][4096] with plain coalesced stores;
// fold_kernel sums the KSPLIT partials. LDS double-buffered (one barrier per
// K-iter); T14 async-STAGE: next chunk's global loads are issued before the
// barrier and stay in flight across the MFMA phase.
// __launch_bounds__(256,4): 4 blocks/CU (LDS 34.8 KB * 4 = 139 KB), VGPR<=128.
// ---------------------------------------------------------------------------
__global__ __launch_bounds__(256, 4) void gram_kernel(const float* __restrict__ x,
                                                      float* __restrict__ gpart) {
  const int b  = blockIdx.x & (BATCH - 1);
  const int ks = blockIdx.x >> 6;
  const float* __restrict__ xb = x + (size_t)b * CH * WFLAT + (size_t)ks * KPER;

  __shared__ unsigned short smem[2][CH * LDSS];   // 2 x 17408 B

  const int tid  = threadIdx.x;
  const int wave = tid >> 6;
  const int lane = tid & 63;
  const int quad = lane >> 4;
  const int l15  = lane & 15;

  // Staging decomposition: row = r*8 + (tid>>5), float4-col = tid&31
  // (each wave loads 2 rows x 32 float4 = two coalesced 512B runs).
  const int trow = tid >> 5;
  const int c4   = tid & 31;
  const float* __restrict__ px = xb + (size_t)trow * WFLAT + c4 * 4;

  f32x4 acc[4];
#pragma unroll
  for (int n = 0; n < 4; n++) acc[n] = (f32x4){0.f, 0.f, 0.f, 0.f};

  // Prologue: fetch chunk 0 into registers (8 float4 = 32 VGPR).
  float4 stage[8];
#pragma unroll
  for (int r = 0; r < 8; r++)
    stage[r] = *(const float4*)(px + (size_t)r * 8 * WFLAT);

  for (int t = 0; t < NT; t++) {
    const int buf = t & 1;
    // Convert staged fp32 -> bf16 pairs, write 64x128 chunk into LDS[buf].
    // (Safe vs. readers of buf at t-2: their reads precede barrier(t-1).)
#pragma unroll
    for (int r = 0; r < 8; r++) {
      const unsigned int lo = f2bf(stage[r].x) | (f2bf(stage[r].y) << 16);
      const unsigned int hi = f2bf(stage[r].z) | (f2bf(stage[r].w) << 16);
      *(uint2*)(&smem[buf][(r * 8 + trow) * LDSS + c4 * 4]) = make_uint2(lo, hi);
    }

    // Issue next chunk's global loads now; they stay in flight across the
    // barrier + MFMA phase (vmcnt wait lands at next iteration's convert).
    if (t + 1 < NT) {
      const float* __restrict__ pn = px + (size_t)(t + 1) * BK;
#pragma unroll
      for (int r = 0; r < 8; r++)
        stage[r] = *(const float4*)(pn + (size_t)r * 8 * WFLAT);
    }

    __syncthreads();   // LDS[buf] writes visible to all waves

    // 4 MFMA K-steps of 32 over the 128-wide chunk.
    // A-frag: A[m=lane&15][k=quad*8+j]; B-frag: B[k=quad*8+j][n=lane&15].
    // Both operands are rows of x_b (G = x x^T), so load patterns coincide.
    const int arow = (wave * 16 + l15) * LDSS;
#pragma unroll
    for (int kk = 0; kk < BK; kk += 32) {
      const int koff = kk + quad * 8;
      const bf16x8 a = *(const bf16x8*)(&smem[buf][arow + koff]);
#pragma unroll
      for (int n = 0; n < 4; n++) {
        const bf16x8 bb = *(const bf16x8*)(&smem[buf][(n * 16 + l15) * LDSS + koff]);
        acc[n] = __builtin_amdgcn_mfma_f32_16x16x32_bf16(a, bb, acc[n], 0, 0, 0);
      }
    }
    // No second barrier: next iteration writes the OTHER buffer, and the
    // following __syncthreads() separates reads(t) from writes(t+2).
  }

  // Epilogue: C/D mapping col=lane&15, row=quad*4+reg. Plain stores to the
  // block-private partial slab (fold_kernel applies the 1/(C*W) scale).
  float* gb = gpart + ((size_t)b * KSPLIT + ks) * GSIZE;
#pragma unroll
  for (int n = 0; n < 4; n++) {
#pragma unroll
    for (int r = 0; r < 4; r++) {
      const int row = wave * 16 + quad * 4 + r;
      const int col = n * 16 + l15;
      gb[row * CH + col] = acc[n][r];
    }
  }
}

// ---------------------------------------------------------------------------
// Kernel 1b: fold the KSPLIT partials into g[b] and apply the Gram scale.
// grid = 64 b x 4 quarters, 256 threads; each thread sums 16 float4s.
// ---------------------------------------------------------------------------
__global__ __launch_bounds__(256) void fold_kernel(const float* __restrict__ gpart,
                                                   float* __restrict__ g) {
  const int b = blockIdx.x & 63;
  const int q = blockIdx.x >> 6;
  const int e = q * 256 + threadIdx.x;            // float4 index 0..1023
  const float4* __restrict__ src =
      (const float4*)(gpart + (size_t)b * KSPLIT * GSIZE) + e;
  float4 s = make_float4(0.f, 0.f, 0.f, 0.f);
#pragma unroll
  for (int ks = 0; ks < KSPLIT; ks++) {
    const float4 v = src[ks * (GSIZE / 4)];
    s.x += v.x; s.y += v.y; s.z += v.z; s.w += v.w;
  }
  const float scale = 1.0f / ((float)CH * (float)WFLAT);
  ((float4*)(g + (size_t)b * GSIZE))[e] =
      make_float4(s.x * scale, s.y * scale, s.z * scale, s.w * scale);
}

// ---------------------------------------------------------------------------
// Kernel 2: pairwise distances D[i][j] = mean((G_i - G_j)^2), element-sliced.
// grid = 64 i-blocks x 4 slices of 256 threads; 4 threads per j, each slice
// covers 256 of the 1024 float4 elements. Partials written to dpart[slice];
// the loss kernel folds the 4 slices. Direct difference form avoids the
// sq/dot cancellation.
// ---------------------------------------------------------------------------
__global__ __launch_bounds__(256) void dist_kernel(const float* __restrict__ g,
                                                   float* __restrict__ dpart) {
  const int i  = blockIdx.x & 63;
  const int sl = blockIdx.x >> 6;          // 0..3
  const int tid = threadIdx.x;
  __shared__ float4 gi4[256];              // 4 KB slice of G_i

  const float4* gsrc = (const float4*)(g + (size_t)i * GSIZE) + sl * 256;
  gi4[tid] = gsrc[tid];
  __syncthreads();

  const int j = tid >> 2;
  const int s = tid & 3;
  const float4* gj = (const float4*)(g + (size_t)j * GSIZE) + sl * 256;

  float acc = 0.f;
#pragma unroll 4
  for (int it = 0; it < 64; it++) {
    const int e = it * 4 + s;
    const float4 a  = gi4[e];
    const float4 bv = gj[e];
    const float d0 = a.x - bv.x, d1 = a.y - bv.y;
    const float d2 = a.z - bv.z, d3 = a.w - bv.w;
    acc = fmaf(d0, d0, acc);
    acc = fmaf(d1, d1, acc);
    acc = fmaf(d2, d2, acc);
    acc = fmaf(d3, d3, acc);
  }
  acc += __shfl_xor(acc, 1);
  acc += __shfl_xor(acc, 2);
  if (s == 0) dpart[sl * 4096 + i * 64 + j] = acc * (1.0f / 4096.0f);
}

// ---------------------------------------------------------------------------
// Kernel 3: loss epilogue. One wave; lane i owns row i.
// Sn[i] = sum_k [t_k != t_i] exp(1 - D[i,k]);
// loss = sum_{i<j, t_i==t_j} relu(log(Sn_i+Sn_j) + D[i,j])^2 / (2P)
// NOTE: harness delivers integer inputs as int32 (NOT the reference's int64).
// ---------------------------------------------------------------------------
__global__ __launch_bounds__(64) void loss_kernel(const float* __restrict__ dpart,
                                                  const int* __restrict__ target,
                                                  float* __restrict__ out) {
  __shared__ float dsh[64 * 64];
  __shared__ int   tsh[64];
  __shared__ float snsh[64];
  const int lane = threadIdx.x;

  for (int e = lane; e < 4096; e += 64)
    dsh[e] = dpart[e] + dpart[4096 + e] + dpart[8192 + e] + dpart[12288 + e];
  tsh[lane] = target[lane];
  __syncthreads();

  const int ti = tsh[lane];
  float sn = 0.f;
  for (int k = 0; k < 64; k++) {
    if (tsh[k] != ti) sn += expf(1.0f - dsh[lane * 64 + k]);
  }
  snsh[lane] = sn;
  __syncthreads();

  float lp = 0.f;
  int   pc = 0;
  for (int j = lane + 1; j < 64; j++) {
    if (tsh[j] == ti) {
      const float Jv = logf(sn + snsh[j]) + dsh[lane * 64 + j];
      const float r  = fmaxf(Jv, 0.f);
      lp = fmaf(r, r, lp);
      pc++;
    }
  }
#pragma unroll
  for (int off = 32; off >= 1; off >>= 1) {
    lp += __shfl_down(lp, off);
    pc += __shfl_down(pc, off);
  }
  if (lane == 0) out[0] = lp / (2.0f * (float)pc);
}

// ---------------------------------------------------------------------------
extern "C" void kernel_launch(void* const* d_in, const int* in_sizes, int n_in,
                              void* d_out, int out_size, void* d_ws, size_t ws_size,
                              hipStream_t stream) {
  const float* x      = (const float*)d_in[0];
  const int*   target = (const int*)d_in[1];   // int inputs arrive as int32
  float* out = (float*)d_out;

  float* gpart = (float*)d_ws;                          // 64*16*4096 fp32 = 16 MB
  float* g     = gpart + (size_t)BATCH * KSPLIT * GSIZE; // 64*4096 fp32 = 1 MB
  float* dpart = g + (size_t)BATCH * GSIZE;             // 4*64*64 fp32 = 64 KB

  // No memset needed: gpart is fully written by gram_kernel each launch.
  gram_kernel<<<BATCH * KSPLIT, 256, 0, stream>>>(x, gpart);
  fold_kernel<<<BATCH * 4, 256, 0, stream>>>(gpart, g);
  dist_kernel<<<BATCH * 4, 256, 0, stream>>>(g, dpart);
  loss_kernel<<<1, 64, 0, stream>>>(dpart, target, out);
}

// Round 10
// 425.715 us; speedup vs baseline: 1.0021x; 1.0021x over previous
//
#include <hip/hip_runtime.h>

// Problem constants
#define BATCH  64
#define CH     64
#define WFLAT  16384              // 128*128
#define KSPLIT 16                 // 1024 blocks = 3-4 blocks/CU
#define KPER   (WFLAT / KSPLIT)   // 1024
#define BK     128                // K-chunk staged in LDS per iteration
#define NT     (KPER / BK)        // 8 iterations per block
#define LDSS   136                // LDS row stride in bf16 elements (128 + 8 pad)
#define GSIZE  (CH * CH)          // 4096

typedef short bf16x8 __attribute__((ext_vector_type(8)));
typedef float f32x4  __attribute__((ext_vector_type(4)));

__device__ __forceinline__ unsigned int f2bf(float f) {
  // fp32 -> bf16 bits, round-to-nearest-even; low 16 bits valid
  unsigned int u = __float_as_uint(f);
  return (u + 0x7FFFu + ((u >> 16) & 1u)) >> 16;
}

// ---------------------------------------------------------------------------
// Kernel 1: batched Gram partials with K-split. NO atomics: block (b, ks)
// writes its 64x64 partial to gpart[b][ks][4096] with plain coalesced stores;
// fold_kernel sums the KSPLIT partials. LDS double-buffered (one barrier per
// K-iter); T14 async-STAGE: next chunk's global loads are issued before the
// barrier and stay in flight across the MFMA phase.
// __launch_bounds__(256,3): VGPR cap ~170 — stage[8] (32 VGPR) + acc + frags
// must NOT spill (A/B vs round-5's (256,4)/128-cap which may have spilled
// stage[] to scratch). min-waves is a floor: if usage <=128 the HW still
// runs 4 blocks/CU (LDS 34.8 KB * 4 = 139 KB < 160 KB).
// ---------------------------------------------------------------------------
__global__ __launch_bounds__(256, 3) void gram_kernel(const float* __restrict__ x,
                                                      float* __restrict__ gpart) {
  const int b  = blockIdx.x & (BATCH - 1);
  const int ks = blockIdx.x >> 6;
  const float* __restrict__ xb = x + (size_t)b * CH * WFLAT + (size_t)ks * KPER;

  __shared__ unsigned short smem[2][CH * LDSS];   // 2 x 17408 B

  const int tid  = threadIdx.x;
  const int wave = tid >> 6;
  const int lane = tid & 63;
  const int quad = lane >> 4;
  const int l15  = lane & 15;

  // Staging decomposition: row = r*8 + (tid>>5), float4-col = tid&31
  // (each wave loads 2 rows x 32 float4 = two coalesced 512B runs).
  const int trow = tid >> 5;
  const int c4   = tid & 31;
  const float* __restrict__ px = xb + (size_t)trow * WFLAT + c4 * 4;

  f32x4 acc[4];
#pragma unroll
  for (int n = 0; n < 4; n++) acc[n] = (f32x4){0.f, 0.f, 0.f, 0.f};

  // Prologue: fetch chunk 0 into registers (8 float4 = 32 VGPR).
  float4 stage[8];
#pragma unroll
  for (int r = 0; r < 8; r++)
    stage[r] = *(const float4*)(px + (size_t)r * 8 * WFLAT);

  for (int t = 0; t < NT; t++) {
    const int buf = t & 1;
    // Convert staged fp32 -> bf16 pairs, write 64x128 chunk into LDS[buf].
    // (Safe vs. readers of buf at t-2: their reads precede barrier(t-1).)
#pragma unroll
    for (int r = 0; r < 8; r++) {
      const unsigned int lo = f2bf(stage[r].x) | (f2bf(stage[r].y) << 16);
      const unsigned int hi = f2bf(stage[r].z) | (f2bf(stage[r].w) << 16);
      *(uint2*)(&smem[buf][(r * 8 + trow) * LDSS + c4 * 4]) = make_uint2(lo, hi);
    }

    // Issue next chunk's global loads now; they stay in flight across the
    // barrier + MFMA phase (vmcnt wait lands at next iteration's convert).
    if (t + 1 < NT) {
      const float* __restrict__ pn = px + (size_t)(t + 1) * BK;
#pragma unroll
      for (int r = 0; r < 8; r++)
        stage[r] = *(const float4*)(pn + (size_t)r * 8 * WFLAT);
    }

    __syncthreads();   // LDS[buf] writes visible to all waves

    // 4 MFMA K-steps of 32 over the 128-wide chunk.
    // A-frag: A[m=lane&15][k=quad*8+j]; B-frag: B[k=quad*8+j][n=lane&15].
    // Both operands are rows of x_b (G = x x^T), so load patterns coincide.
    const int arow = (wave * 16 + l15) * LDSS;
#pragma unroll
    for (int kk = 0; kk < BK; kk += 32) {
      const int koff = kk + quad * 8;
      const bf16x8 a = *(const bf16x8*)(&smem[buf][arow + koff]);
#pragma unroll
      for (int n = 0; n < 4; n++) {
        const bf16x8 bb = *(const bf16x8*)(&smem[buf][(n * 16 + l15) * LDSS + koff]);
        acc[n] = __builtin_amdgcn_mfma_f32_16x16x32_bf16(a, bb, acc[n], 0, 0, 0);
      }
    }
    // No second barrier: next iteration writes the OTHER buffer, and the
    // following __syncthreads() separates reads(t) from writes(t+2).
  }

  // Epilogue: C/D mapping col=lane&15, row=quad*4+reg. Plain stores to the
  // block-private partial slab (fold_kernel applies the 1/(C*W) scale).
  float* gb = gpart + ((size_t)b * KSPLIT + ks) * GSIZE;
#pragma unroll
  for (int n = 0; n < 4; n++) {
#pragma unroll
    for (int r = 0; r < 4; r++) {
      const int row = wave * 16 + quad * 4 + r;
      const int col = n * 16 + l15;
      gb[row * CH + col] = acc[n][r];
    }
  }
}

// ---------------------------------------------------------------------------
// Kernel 1b: fold the KSPLIT partials into g[b] and apply the Gram scale.
// grid = 64 b x 4 quarters, 256 threads; each thread sums 16 float4s.
// ---------------------------------------------------------------------------
__global__ __launch_bounds__(256) void fold_kernel(const float* __restrict__ gpart,
                                                   float* __restrict__ g) {
  const int b = blockIdx.x & 63;
  const int q = blockIdx.x >> 6;
  const int e = q * 256 + threadIdx.x;            // float4 index 0..1023
  const float4* __restrict__ src =
      (const float4*)(gpart + (size_t)b * KSPLIT * GSIZE) + e;
  float4 s = make_float4(0.f, 0.f, 0.f, 0.f);
#pragma unroll
  for (int ks = 0; ks < KSPLIT; ks++) {
    const float4 v = src[ks * (GSIZE / 4)];
    s.x += v.x; s.y += v.y; s.z += v.z; s.w += v.w;
  }
  const float scale = 1.0f / ((float)CH * (float)WFLAT);
  ((float4*)(g + (size_t)b * GSIZE))[e] =
      make_float4(s.x * scale, s.y * scale, s.z * scale, s.w * scale);
}

// ---------------------------------------------------------------------------
// Kernel 2: pairwise distances D[i][j] = mean((G_i - G_j)^2), element-sliced.
// grid = 64 i-blocks x 4 slices of 256 threads; 4 threads per j, each slice
// covers 256 of the 1024 float4 elements. Partials written to dpart[slice];
// the loss kernel folds the 4 slices. Direct difference form avoids the
// sq/dot cancellation.
// ---------------------------------------------------------------------------
__global__ __launch_bounds__(256) void dist_kernel(const float* __restrict__ g,
                                                   float* __restrict__ dpart) {
  const int i  = blockIdx.x & 63;
  const int sl = blockIdx.x >> 6;          // 0..3
  const int tid = threadIdx.x;
  __shared__ float4 gi4[256];              // 4 KB slice of G_i

  const float4* gsrc = (const float4*)(g + (size_t)i * GSIZE) + sl * 256;
  gi4[tid] = gsrc[tid];
  __syncthreads();

  const int j = tid >> 2;
  const int s = tid & 3;
  const float4* gj = (const float4*)(g + (size_t)j * GSIZE) + sl * 256;

  float acc = 0.f;
#pragma unroll 4
  for (int it = 0; it < 64; it++) {
    const int e = it * 4 + s;
    const float4 a  = gi4[e];
    const float4 bv = gj[e];
    const float d0 = a.x - bv.x, d1 = a.y - bv.y;
    const float d2 = a.z - bv.z, d3 = a.w - bv.w;
    acc = fmaf(d0, d0, acc);
    acc = fmaf(d1, d1, acc);
    acc = fmaf(d2, d2, acc);
    acc = fmaf(d3, d3, acc);
  }
  acc += __shfl_xor(acc, 1);
  acc += __shfl_xor(acc, 2);
  if (s == 0) dpart[sl * 4096 + i * 64 + j] = acc * (1.0f / 4096.0f);
}

// ---------------------------------------------------------------------------
// Kernel 3: loss epilogue. One wave; lane i owns row i.
// Sn[i] = sum_k [t_k != t_i] exp(1 - D[i,k]);
// loss = sum_{i<j, t_i==t_j} relu(log(Sn_i+Sn_j) + D[i,j])^2 / (2P)
// NOTE: harness delivers integer inputs as int32 (NOT the reference's int64).
// ---------------------------------------------------------------------------
__global__ __launch_bounds__(64) void loss_kernel(const float* __restrict__ dpart,
                                                  const int* __restrict__ target,
                                                  float* __restrict__ out) {
  __shared__ float dsh[64 * 64];
  __shared__ int   tsh[64];
  __shared__ float snsh[64];
  const int lane = threadIdx.x;

  for (int e = lane; e < 4096; e += 64)
    dsh[e] = dpart[e] + dpart[4096 + e] + dpart[8192 + e] + dpart[12288 + e];
  tsh[lane] = target[lane];
  __syncthreads();

  const int ti = tsh[lane];
  float sn = 0.f;
  for (int k = 0; k < 64; k++) {
    if (tsh[k] != ti) sn += expf(1.0f - dsh[lane * 64 + k]);
  }
  snsh[lane] = sn;
  __syncthreads();

  float lp = 0.f;
  int   pc = 0;
  for (int j = lane + 1; j < 64; j++) {
    if (tsh[j] == ti) {
      const float Jv = logf(sn + snsh[j]) + dsh[lane * 64 + j];
      const float r  = fmaxf(Jv, 0.f);
      lp = fmaf(r, r, lp);
      pc++;
    }
  }
#pragma unroll
  for (int off = 32; off >= 1; off >>= 1) {
    lp += __shfl_down(lp, off);
    pc += __shfl_down(pc, off);
  }
  if (lane == 0) out[0] = lp / (2.0f * (float)pc);
}

// ---------------------------------------------------------------------------
extern "C" void kernel_launch(void* const* d_in, const int* in_sizes, int n_in,
                              void* d_out, int out_size, void* d_ws, size_t ws_size,
                              hipStream_t stream) {
  const float* x      = (const float*)d_in[0];
  const int*   target = (const int*)d_in[1];   // int inputs arrive as int32
  float* out = (float*)d_out;

  float* gpart = (float*)d_ws;                          // 64*16*4096 fp32 = 16 MB
  float* g     = gpart + (size_t)BATCH * KSPLIT * GSIZE; // 64*4096 fp32 = 1 MB
  float* dpart = g + (size_t)BATCH * GSIZE;             // 4*64*64 fp32 = 64 KB

  // No memset needed: gpart is fully written by gram_kernel each launch.
  gram_kernel<<<BATCH * KSPLIT, 256, 0, stream>>>(x, gpart);
  fold_kernel<<<BATCH * 4, 256, 0, stream>>>(gpart, g);
  dist_kernel<<<BATCH * 4, 256, 0, stream>>>(g, dpart);
  loss_kernel<<<1, 64, 0, stream>>>(dpart, target, out);
}